// Round 10
// baseline (191.689 us; speedup 1.0000x reference)
//
#include <hip/hip_runtime.h>
#include <hip/hip_bf16.h>

typedef __bf16 bf16x8 __attribute__((ext_vector_type(8)));
typedef __bf16 bf16x4 __attribute__((ext_vector_type(4)));
typedef float f32x4 __attribute__((ext_vector_type(4)));

#define SLEN 2048
#define NHEADS 16
#define HDIM 64

// ---------------- prep (R8-exact) ----------------
// blocks 0..4095: cast hidden fp32->bf16; 4096..7167: Wqkv B-frag; 7168..8191: Wo B-frag
__global__ __launch_bounds__(256) void prep(const float* __restrict__ hidden,
                                            const float* __restrict__ Wqkv,
                                            const float* __restrict__ Wo,
                                            __bf16* __restrict__ A1,
                                            __bf16* __restrict__ Wt,
                                            __bf16* __restrict__ Wot) {
    int b = blockIdx.x;
    if (b < 4096) {
        int i = b * 256 + threadIdx.x;
        float4 v = reinterpret_cast<const float4*>(hidden)[i];
        bf16x4 o = { (__bf16)v.x, (__bf16)v.y, (__bf16)v.z, (__bf16)v.w };
        reinterpret_cast<bf16x4*>(A1)[i] = o;
        return;
    }
    __shared__ float tile[32][33];
    const float* W; __bf16* Dst; int N, n0, kc, bx, wn, j0, JNv;
    if (b < 7168) {
        int bb = b - 4096;                       // 96 n-tiles x 32 k-tiles
        int bx96 = bb % 96; kc = bb / 96;
        W = Wqkv; Dst = Wt; N = 3072;
        n0 = bx96 * 32;
        bx = bx96 >> 2; wn = (bx96 >> 1) & 1; j0 = (bx96 & 1) * 2; JNv = 4;
    } else {
        int bb = b - 7168;                       // 32 n-tiles x 32 k-tiles
        int bx32 = bb % 32; kc = bb / 32;
        W = Wo; Dst = Wot; N = 1024;
        n0 = bx32 * 32;
        bx = bx32 >> 1; wn = bx32 & 1; j0 = 0; JNv = 2;
    }
    int k0 = kc * 32;
    int tx = threadIdx.x & 31, ty = threadIdx.x >> 5;
    #pragma unroll
    for (int i = ty; i < 32; i += 8)
        tile[i][tx] = W[(size_t)(k0 + i) * N + n0 + tx];
    __syncthreads();
    if (threadIdx.x < 128) {
        int jh = threadIdx.x >> 6;
        int lane = threadIdx.x & 63;
        int lrow = lane & 15, quad = lane >> 4;
        bf16x8 val;
        #pragma unroll
        for (int i = 0; i < 8; i++)
            val[i] = (__bf16)tile[quad * 8 + i][jh * 16 + lrow];
        size_t idx = ((((size_t)(bx * 32 + kc) * 2 + wn) * JNv + (j0 + jh)) * 64 + lane);
        *reinterpret_cast<bf16x8*>(Dst + idx * 8) = val;
    }
}

// ---------------- GEMM: A staged in LDS, B fragment-linear (R7-exact loop) ---------
// epi==0: fp32 out + bias. epi==1: Q,K -> [B][H][S][D]; V -> TRANSPOSED [B][H][D][S]
// (V^T writes are bf16x4 vector stores: C/D layout's 4 acc rows = 4 consecutive s).
template <int TN>
__global__ __launch_bounds__(256) void gemm_bt(const __bf16* __restrict__ A,
                                               const __bf16* __restrict__ Bfrag,
                                               const float* __restrict__ bias,
                                               float* __restrict__ Cf,
                                               __bf16* __restrict__ Cq,
                                               __bf16* __restrict__ Ck,
                                               __bf16* __restrict__ Cv,
                                               int M, int N, int K, int epi) {
    constexpr int JN = TN / 32;   // n-frags per wave
    __shared__ __align__(16) __bf16 As[128 * 40];

    int nb = N / TN;
    int bx = blockIdx.x % nb;
    int by = blockIdx.x / nb;
    int row0 = by * 128, col0 = bx * TN;

    int tid = threadIdx.x;
    int wave = tid >> 6, lane = tid & 63;
    int quad = lane >> 4, lrow = lane & 15;
    int wm = wave >> 1, wn = wave & 1;

    int r1 = tid >> 2;
    int kk = (tid & 3) * 8;
    const __bf16* Aptr = A + (size_t)(row0 + r1) * K + kk;

    const __bf16* Bbase = Bfrag + ((size_t)(bx * 32) * 2 + wn) * JN * 512 + (size_t)lane * 8;

    f32x4 acc[4][JN];
    f32x4 zero = {0.f, 0.f, 0.f, 0.f};
    #pragma unroll
    for (int i = 0; i < 4; i++)
        #pragma unroll
        for (int j = 0; j < JN; j++) acc[i][j] = zero;

    int nkc = K >> 5;
    for (int kc = 0; kc < nkc; kc++) {
        int k0 = kc * 32;
        bf16x8 a0 = *reinterpret_cast<const bf16x8*>(Aptr + k0);
        bf16x8 a1 = *reinterpret_cast<const bf16x8*>(Aptr + (size_t)64 * K + k0);
        bf16x8 bfr[JN];
        #pragma unroll
        for (int j = 0; j < JN; j++)
            bfr[j] = *reinterpret_cast<const bf16x8*>(Bbase + (size_t)kc * JN * 1024 + j * 512);
        __syncthreads();
        *reinterpret_cast<bf16x8*>(&As[r1 * 40 + kk]) = a0;
        *reinterpret_cast<bf16x8*>(&As[(r1 + 64) * 40 + kk]) = a1;
        __syncthreads();

        bf16x8 af[4];
        #pragma unroll
        for (int i = 0; i < 4; i++)
            af[i] = *reinterpret_cast<const bf16x8*>(&As[(wm * 64 + i * 16 + lrow) * 40 + quad * 8]);
        #pragma unroll
        for (int i = 0; i < 4; i++)
            #pragma unroll
            for (int j = 0; j < JN; j++)
                acc[i][j] = __builtin_amdgcn_mfma_f32_16x16x32_bf16(af[i], bfr[j], acc[i][j], 0, 0, 0);
    }

    int part = col0 >> 10;          // block-uniform
    #pragma unroll
    for (int i = 0; i < 4; i++) {
        int rowb = row0 + wm * 64 + i * 16 + quad * 4;
        #pragma unroll
        for (int j = 0; j < JN; j++) {
            int col = col0 + wn * (TN / 2) + j * 16 + lrow;
            float bsv = bias[col];
            if (epi == 0) {
                #pragma unroll
                for (int r = 0; r < 4; r++)
                    Cf[(size_t)(rowb + r) * N + col] = acc[i][j][r] + bsv;
            } else {
                int h = (col >> 6) & 15;
                int d = col & 63;
                int b = rowb >> 11;
                int s0 = rowb & 2047;
                if (part == 2) {
                    // V transposed: [B][H][D][S], 4 consecutive s -> vector store
                    bf16x4 vv;
                    #pragma unroll
                    for (int r = 0; r < 4; r++) vv[r] = (__bf16)(acc[i][j][r] + bsv);
                    *reinterpret_cast<bf16x4*>(Cv + ((size_t)(b * NHEADS + h) * HDIM + d) * SLEN + s0) = vv;
                } else {
                    __bf16* dst = (part == 0) ? Cq : Ck;
                    #pragma unroll
                    for (int r = 0; r < 4; r++)
                        dst[((size_t)(b * NHEADS + h) * SLEN + s0 + r) * HDIM + d] = (__bf16)(acc[i][j][r] + bsv);
                }
            }
        }
    }
}

// ---- apply rope to an 8-elem group (4 complete pairs in-lane, no shuffles) ----
__device__ __forceinline__ bf16x8 rope8(bf16x8 v, f32x4 a, f32x4 b) {
    bf16x8 o;
    float e, od;
    e = (float)v[0]; od = (float)v[1];
    o[0] = (__bf16)(e * a[0] - od * a[1]); o[1] = (__bf16)(od * a[0] + e * a[1]);
    e = (float)v[2]; od = (float)v[3];
    o[2] = (__bf16)(e * a[2] - od * a[3]); o[3] = (__bf16)(od * a[2] + e * a[3]);
    e = (float)v[4]; od = (float)v[5];
    o[4] = (__bf16)(e * b[0] - od * b[1]); o[5] = (__bf16)(od * b[0] + e * b[1]);
    e = (float)v[6]; od = (float)v[7];
    o[6] = (__bf16)(e * b[2] - od * b[3]); o[7] = (__bf16)(od * b[2] + e * b[3]);
    return o;
}

// ---------------- RoPE in place on Q,K  [BH][S][64], vectorized x8 (R8-exact) ------
__global__ __launch_bounds__(256) void rope_kernel(__bf16* __restrict__ Q,
                                                   __bf16* __restrict__ K,
                                                   const float* __restrict__ rope) {
    int idx = blockIdx.x * 256 + threadIdx.x;        // [0, 32*2048*8)
    int chunk = idx & 7;
    int s = (idx >> 3) & 2047;
    int bh = idx >> 14;
    size_t off = ((size_t)bh * SLEN + s) * HDIM + chunk * 8;
    int pos = s & 255;
    const float* rp = rope + (size_t)pos * 64 + chunk * 8;
    f32x4 a = *reinterpret_cast<const f32x4*>(rp);
    f32x4 b = *reinterpret_cast<const f32x4*>(rp + 4);
    bf16x8 qv = *reinterpret_cast<bf16x8*>(Q + off);
    *reinterpret_cast<bf16x8*>(Q + off) = rope8(qv, a, b);
    bf16x8 kv = *reinterpret_cast<bf16x8*>(K + off);
    *reinterpret_cast<bf16x8*>(K + off) = rope8(kv, a, b);
}

// ---------------- windowed attention v5: V^T from global, zero LDS-staging ---------
// grid: BH(32) x qtiles(32); block = 4 waves; wave owns 16 queries. ZERO barriers.
// K and V^T fragments both pair-prefetched 2 chunks ahead from global; LDS = Pl only.
__global__ __launch_bounds__(256) void attn_kernel(const __bf16* __restrict__ Q,
                                                   const __bf16* __restrict__ K,
                                                   const __bf16* __restrict__ Vt,
                                                   __bf16* __restrict__ O) {
    __shared__ __align__(16) __bf16 Pl[4][16][80];   // per-wave P roundtrip, 2 slots

    int qt = blockIdx.x & 31;
    int bh = blockIdx.x >> 5;
    int q0 = qt * 64;
    int kbase0 = q0 - 128;
    const __bf16* Qbh = Q + (size_t)bh * SLEN * HDIM;
    const __bf16* Kbh = K + (size_t)bh * SLEN * HDIM;
    const __bf16* Vbh = Vt + (size_t)bh * SLEN * HDIM;   // [64][2048]

    int tid = threadIdx.x;
    int wave = tid >> 6, lane = tid & 63;
    int quad = lane >> 4, lrow = lane & 15;
    int wq0 = q0 + wave * 16;

    // Q B-fragments (loop-invariant): lane holds Q[wq0+lrow][quad*8+j]
    bf16x8 qb0 = *reinterpret_cast<const bf16x8*>(Qbh + (size_t)(wq0 + lrow) * HDIM + quad * 8);
    bf16x8 qb1 = *reinterpret_cast<const bf16x8*>(Qbh + (size_t)(wq0 + lrow) * HDIM + 32 + quad * 8);

    f32x4 zero = {0.f, 0.f, 0.f, 0.f};
    f32x4 acc[4], acc_l = zero;
    #pragma unroll
    for (int t = 0; t < 4; t++) acc[t] = zero;

    bf16x8 ones = { (__bf16)1.f, (__bf16)1.f, (__bf16)1.f, (__bf16)1.f,
                    (__bf16)1.f, (__bf16)1.f, (__bf16)1.f, (__bf16)1.f };

    // wave-uniform chunk range (32-key chunks rel. to kbase0); in-range chunks are
    // fully in-bounds: kbase0 + cbeg*32 >= 0 and kbase0 + cend*32 + 32 <= SLEN.
    int cbeg = wave >> 1;
    if (q0 < 128) { int e = (128 - q0) >> 5; if (e > cbeg) cbeg = e; }
    int cend = (16 * wave + 271) >> 5;
    { int e = (2175 - q0) >> 5; if (e < cend) cend = e; }

    auto loadK = [&](int c, bf16x8 (&kf)[2][2]) {
        int kb = kbase0 + c * 32;
        #pragma unroll
        for (int sub = 0; sub < 2; sub++) {
            int kr = kb + sub * 16 + lrow;
            int krc = min(max(kr, 0), SLEN - 1);     // clamp: prefetch past cend safe
            const __bf16* kp = Kbh + (size_t)krc * HDIM;
            kf[sub][0] = *reinterpret_cast<const bf16x8*>(kp + quad * 8);
            kf[sub][1] = *reinterpret_cast<const bf16x8*>(kp + 32 + quad * 8);
        }
    };
    auto loadV = [&](int c, bf16x8 (&vf)[4]) {
        int col = kbase0 + c * 32;
        col = min(max(col, 0), SLEN - 32);           // clamp: prefetch past cend safe
        #pragma unroll
        for (int t = 0; t < 4; t++)
            vf[t] = *reinterpret_cast<const bf16x8*>(Vbh + (size_t)(t * 16 + lrow) * SLEN + col + quad * 8);
    };

    // QK^T + mask + exp -> P slot
    auto qkExp = [&](int c, bf16x8 (&kf)[2][2], int slot) {
        int kb = kbase0 + c * 32;
        int q = wq0 + lrow;
        #pragma unroll
        for (int sub = 0; sub < 2; sub++) {
            f32x4 st = __builtin_amdgcn_mfma_f32_16x16x32_bf16(kf[sub][0], qb0, zero, 0, 0, 0);
            st = __builtin_amdgcn_mfma_f32_16x16x32_bf16(kf[sub][1], qb1, st, 0, 0, 0);
            bf16x4 pk;
            #pragma unroll
            for (int r = 0; r < 4; r++) {
                int key = kb + sub * 16 + quad * 4 + r;
                int rel = key - q;
                bool valid = (rel >= -128) && (rel <= 128);
                pk[r] = (__bf16)(valid ? __expf(st[r] * 0.125f) : 0.0f);
            }
            *reinterpret_cast<bf16x4*>(&Pl[wave][lrow][slot * 40 + sub * 16 + quad * 4]) = pk;
        }
    };

    // P B-fragment read + PV + row-sum (V^T A-operand from registers)
    auto pv = [&](bf16x8 (&vf)[4], int slot) {
        bf16x8 bp = *reinterpret_cast<const bf16x8*>(&Pl[wave][lrow][slot * 40 + quad * 8]);
        acc_l = __builtin_amdgcn_mfma_f32_16x16x32_bf16(ones, bp, acc_l, 0, 0, 0);
        #pragma unroll
        for (int t = 0; t < 4; t++)
            acc[t] = __builtin_amdgcn_mfma_f32_16x16x32_bf16(vf[t], bp, acc[t], 0, 0, 0);
    };

    bf16x8 ka0[2][2], ka1[2][2], va0[4], va1[4];
    loadK(cbeg, ka0); loadV(cbeg, va0);
    loadK(cbeg + 1, ka1); loadV(cbeg + 1, va1);      // clamped-safe if cbeg+1 > cend
    int c = cbeg;
    while (c + 1 <= cend) {
        bf16x8 kn0[2][2], kn1[2][2], vn0[4], vn1[4];
        loadK(c + 2, kn0); loadV(c + 2, vn0);
        loadK(c + 3, kn1); loadV(c + 3, vn1);
        qkExp(c, ka0, 0);
        qkExp(c + 1, ka1, 1);
        asm volatile("s_waitcnt lgkmcnt(0)" ::: "memory");  // P writes visible (wave-local)
        pv(va0, 0);
        pv(va1, 1);
        #pragma unroll
        for (int sub = 0; sub < 2; sub++) {
            ka0[sub][0] = kn0[sub][0]; ka0[sub][1] = kn0[sub][1];
            ka1[sub][0] = kn1[sub][0]; ka1[sub][1] = kn1[sub][1];
        }
        #pragma unroll
        for (int t = 0; t < 4; t++) { va0[t] = vn0[t]; va1[t] = vn1[t]; }
        c += 2;
    }
    if (c <= cend) {         // odd-count tail
        qkExp(c, ka0, 0);
        asm volatile("s_waitcnt lgkmcnt(0)" ::: "memory");
        pv(va0, 0);
    }

    // epilogue: lane holds O^T[d=t*16+quad*4+r][q=lrow]; l[q] = acc_l[0]
    float inv = 1.0f / acc_l[0];
    int b = bh >> 4, h = bh & 15;
    int q = wq0 + lrow;
    size_t base = ((size_t)b * SLEN + q) * 1024 + h * HDIM;
    #pragma unroll
    for (int t = 0; t < 4; t++) {
        bf16x4 o;
        #pragma unroll
        for (int r = 0; r < 4; r++) o[r] = (__bf16)(acc[t][r] * inv);
        *reinterpret_cast<bf16x4*>(&O[base + t * 16 + quad * 4]) = o;
    }
}

extern "C" void kernel_launch(void* const* d_in, const int* in_sizes, int n_in,
                              void* d_out, int out_size, void* d_ws, size_t ws_size,
                              hipStream_t stream) {
    const float* hidden = (const float*)d_in[0];   // [2,2048,1024]
    const float* Wqkv   = (const float*)d_in[1];   // [1024,3072]
    const float* bqkv   = (const float*)d_in[2];   // [3072]
    const float* Wo     = (const float*)d_in[3];   // [1024,1024]
    const float* bo     = (const float*)d_in[4];   // [1024]
    const float* rope   = (const float*)d_in[5];   // [256,32,2]
    float* out = (float*)d_out;                    // [2,2048,1024] fp32

    char* ws = (char*)d_ws;
    __bf16* A1  = (__bf16*)(ws);                   //  8 MiB: hidden bf16 [4096][1024]
    __bf16* Wt  = (__bf16*)(ws + 8388608);         //  6 MiB: Wqkv B-frag-linear
    __bf16* Wot = (__bf16*)(ws + 14680064);        //  2 MiB: Wo B-frag-linear
    __bf16* Qb  = (__bf16*)(ws + 16777216);        //  8 MiB: Q [B][H][S][64]
    __bf16* Kb  = (__bf16*)(ws + 25165824);        //  8 MiB: K [B][H][S][64]
    __bf16* Vb  = (__bf16*)(ws + 33554432);        //  8 MiB: V^T [B][H][64][S]
    __bf16* AO  = (__bf16*)(ws + 41943040);        //  8 MiB: attn out [4096][1024]

    // prep: cast hidden; weights -> B-frag-linear
    prep<<<8192, 256, 0, stream>>>(hidden, Wqkv, Wo, A1, Wt, Wot);

    // QKV projection: -> Q,K [B][H][S][64]; V transposed [B][H][64][S]
    gemm_bt<128><<<32 * 24, 256, 0, stream>>>(A1, Wt, bqkv, nullptr, Qb, Kb, Vb,
                                              4096, 3072, 1024, 1);
    // RoPE on Q,K in place (vectorized x8)
    rope_kernel<<<2048, 256, 0, stream>>>(Qb, Kb, rope);
    // windowed attention (V^T from global, zero-barrier) -> AO [4096][1024] bf16
    attn_kernel<<<1024, 256, 0, stream>>>(Qb, Kb, Vb, AO);
    // output projection: [4096,1024]@[1024,1024] + bias -> d_out fp32
    gemm_bt<64><<<32 * 16, 256, 0, stream>>>(AO, Wot, bo, out, nullptr, nullptr, nullptr,
                                             4096, 1024, 1024, 0);
}

// Round 11
// 179.298 us; speedup vs baseline: 1.0691x; 1.0691x over previous
//
#include <hip/hip_runtime.h>
#include <hip/hip_bf16.h>

typedef __bf16 bf16x8 __attribute__((ext_vector_type(8)));
typedef __bf16 bf16x4 __attribute__((ext_vector_type(4)));
typedef float f32x4 __attribute__((ext_vector_type(4)));

#define SLEN 2048
#define NHEADS 16
#define HDIM 64

// ---------------- prep (R8-exact) ----------------
// blocks 0..4095: cast hidden fp32->bf16; 4096..7167: Wqkv B-frag; 7168..8191: Wo B-frag
__global__ __launch_bounds__(256) void prep(const float* __restrict__ hidden,
                                            const float* __restrict__ Wqkv,
                                            const float* __restrict__ Wo,
                                            __bf16* __restrict__ A1,
                                            __bf16* __restrict__ Wt,
                                            __bf16* __restrict__ Wot) {
    int b = blockIdx.x;
    if (b < 4096) {
        int i = b * 256 + threadIdx.x;
        float4 v = reinterpret_cast<const float4*>(hidden)[i];
        bf16x4 o = { (__bf16)v.x, (__bf16)v.y, (__bf16)v.z, (__bf16)v.w };
        reinterpret_cast<bf16x4*>(A1)[i] = o;
        return;
    }
    __shared__ float tile[32][33];
    const float* W; __bf16* Dst; int N, n0, kc, bx, wn, j0, JNv;
    if (b < 7168) {
        int bb = b - 4096;                       // 96 n-tiles x 32 k-tiles
        int bx96 = bb % 96; kc = bb / 96;
        W = Wqkv; Dst = Wt; N = 3072;
        n0 = bx96 * 32;
        bx = bx96 >> 2; wn = (bx96 >> 1) & 1; j0 = (bx96 & 1) * 2; JNv = 4;
    } else {
        int bb = b - 7168;                       // 32 n-tiles x 32 k-tiles
        int bx32 = bb % 32; kc = bb / 32;
        W = Wo; Dst = Wot; N = 1024;
        n0 = bx32 * 32;
        bx = bx32 >> 1; wn = bx32 & 1; j0 = 0; JNv = 2;
    }
    int k0 = kc * 32;
    int tx = threadIdx.x & 31, ty = threadIdx.x >> 5;
    #pragma unroll
    for (int i = ty; i < 32; i += 8)
        tile[i][tx] = W[(size_t)(k0 + i) * N + n0 + tx];
    __syncthreads();
    if (threadIdx.x < 128) {
        int jh = threadIdx.x >> 6;
        int lane = threadIdx.x & 63;
        int lrow = lane & 15, quad = lane >> 4;
        bf16x8 val;
        #pragma unroll
        for (int i = 0; i < 8; i++)
            val[i] = (__bf16)tile[quad * 8 + i][jh * 16 + lrow];
        size_t idx = ((((size_t)(bx * 32 + kc) * 2 + wn) * JNv + (j0 + jh)) * 64 + lane);
        *reinterpret_cast<bf16x8*>(Dst + idx * 8) = val;
    }
}

// ---------------- GEMM: A in ping-pong LDS, B fragment-linear -----------------------
// One barrier per K-iter; A+B for iter k+1 prefetched to regs before iter k's MFMAs.
// epi==0: fp32 out + bias; epi==1: split Q/K/V bf16 [B][H][S][D] + bias.
template <int TN>
__global__ __launch_bounds__(256) void gemm_bt(const __bf16* __restrict__ A,
                                               const __bf16* __restrict__ Bfrag,
                                               const float* __restrict__ bias,
                                               float* __restrict__ Cf,
                                               __bf16* __restrict__ Cq,
                                               __bf16* __restrict__ Ck,
                                               __bf16* __restrict__ Cv,
                                               int M, int N, int K, int epi) {
    constexpr int JN = TN / 32;   // n-frags per wave
    __shared__ __align__(16) __bf16 As[2][128 * 40];

    int nb = N / TN;
    int bx = blockIdx.x % nb;
    int by = blockIdx.x / nb;
    int row0 = by * 128, col0 = bx * TN;

    int tid = threadIdx.x;
    int wave = tid >> 6, lane = tid & 63;
    int quad = lane >> 4, lrow = lane & 15;
    int wm = wave >> 1, wn = wave & 1;

    int r1 = tid >> 2;
    int kk = (tid & 3) * 8;
    const __bf16* Aptr = A + (size_t)(row0 + r1) * K + kk;

    const __bf16* Bbase = Bfrag + ((size_t)(bx * 32) * 2 + wn) * JN * 512 + (size_t)lane * 8;

    f32x4 acc[4][JN];
    f32x4 zero = {0.f, 0.f, 0.f, 0.f};
    #pragma unroll
    for (int i = 0; i < 4; i++)
        #pragma unroll
        for (int j = 0; j < JN; j++) acc[i][j] = zero;

    int nkc = K >> 5;

    // prologue: stage kc=0 into buf 0; hold B frags for kc=0 in regs
    {
        bf16x8 a0 = *reinterpret_cast<const bf16x8*>(Aptr);
        bf16x8 a1 = *reinterpret_cast<const bf16x8*>(Aptr + (size_t)64 * K);
        *reinterpret_cast<bf16x8*>(&As[0][r1 * 40 + kk]) = a0;
        *reinterpret_cast<bf16x8*>(&As[0][(r1 + 64) * 40 + kk]) = a1;
    }
    bf16x8 bR[JN];
    #pragma unroll
    for (int j = 0; j < JN; j++)
        bR[j] = *reinterpret_cast<const bf16x8*>(Bbase + j * 512);
    __syncthreads();

    for (int kc = 0; kc < nkc; kc++) {
        int p = kc & 1;
        bool more = (kc + 1) < nkc;
        bf16x8 aN0, aN1, bN[JN];
        if (more) {
            int k0 = (kc + 1) * 32;
            aN0 = *reinterpret_cast<const bf16x8*>(Aptr + k0);
            aN1 = *reinterpret_cast<const bf16x8*>(Aptr + (size_t)64 * K + k0);
            #pragma unroll
            for (int j = 0; j < JN; j++)
                bN[j] = *reinterpret_cast<const bf16x8*>(Bbase + (size_t)(kc + 1) * JN * 1024 + j * 512);
        }

        bf16x8 af[4];
        #pragma unroll
        for (int i = 0; i < 4; i++)
            af[i] = *reinterpret_cast<const bf16x8*>(&As[p][(wm * 64 + i * 16 + lrow) * 40 + quad * 8]);
        #pragma unroll
        for (int i = 0; i < 4; i++)
            #pragma unroll
            for (int j = 0; j < JN; j++)
                acc[i][j] = __builtin_amdgcn_mfma_f32_16x16x32_bf16(af[i], bR[j], acc[i][j], 0, 0, 0);

        if (more) {
            *reinterpret_cast<bf16x8*>(&As[p ^ 1][r1 * 40 + kk]) = aN0;
            *reinterpret_cast<bf16x8*>(&As[p ^ 1][(r1 + 64) * 40 + kk]) = aN1;
            __syncthreads();
            #pragma unroll
            for (int j = 0; j < JN; j++) bR[j] = bN[j];
        }
    }

    int part = col0 >> 10;          // block-uniform
    #pragma unroll
    for (int i = 0; i < 4; i++) {
        int rowb = row0 + wm * 64 + i * 16 + quad * 4;
        #pragma unroll
        for (int j = 0; j < JN; j++) {
            int col = col0 + wn * (TN / 2) + j * 16 + lrow;
            float bsv = bias[col];
            #pragma unroll
            for (int r = 0; r < 4; r++) {
                int row = rowb + r;
                float v = acc[i][j][r] + bsv;
                if (epi == 0) {
                    Cf[(size_t)row * N + col] = v;
                } else {
                    int h = (col >> 6) & 15;
                    int d = col & 63;
                    int b = row >> 11;
                    int s = row & 2047;
                    __bf16* dst = (part == 0) ? Cq : ((part == 1) ? Ck : Cv);
                    dst[((size_t)(b * NHEADS + h) * SLEN + s) * HDIM + d] = (__bf16)v;
                }
            }
        }
    }
}

// ---- apply rope to an 8-elem group (4 complete pairs in-lane, no shuffles) ----
__device__ __forceinline__ bf16x8 rope8(bf16x8 v, f32x4 a, f32x4 b) {
    bf16x8 o;
    float e, od;
    e = (float)v[0]; od = (float)v[1];
    o[0] = (__bf16)(e * a[0] - od * a[1]); o[1] = (__bf16)(od * a[0] + e * a[1]);
    e = (float)v[2]; od = (float)v[3];
    o[2] = (__bf16)(e * a[2] - od * a[3]); o[3] = (__bf16)(od * a[2] + e * a[3]);
    e = (float)v[4]; od = (float)v[5];
    o[4] = (__bf16)(e * b[0] - od * b[1]); o[5] = (__bf16)(od * b[0] + e * b[1]);
    e = (float)v[6]; od = (float)v[7];
    o[6] = (__bf16)(e * b[2] - od * b[3]); o[7] = (__bf16)(od * b[2] + e * b[3]);
    return o;
}

// ---------------- RoPE in place on Q,K  [BH][S][64], vectorized x8 (R8-exact) ------
__global__ __launch_bounds__(256) void rope_kernel(__bf16* __restrict__ Q,
                                                   __bf16* __restrict__ K,
                                                   const float* __restrict__ rope) {
    int idx = blockIdx.x * 256 + threadIdx.x;        // [0, 32*2048*8)
    int chunk = idx & 7;
    int s = (idx >> 3) & 2047;
    int bh = idx >> 14;
    size_t off = ((size_t)bh * SLEN + s) * HDIM + chunk * 8;
    int pos = s & 255;
    const float* rp = rope + (size_t)pos * 64 + chunk * 8;
    f32x4 a = *reinterpret_cast<const f32x4*>(rp);
    f32x4 b = *reinterpret_cast<const f32x4*>(rp + 4);
    bf16x8 qv = *reinterpret_cast<bf16x8*>(Q + off);
    *reinterpret_cast<bf16x8*>(Q + off) = rope8(qv, a, b);
    bf16x8 kv = *reinterpret_cast<bf16x8*>(K + off);
    *reinterpret_cast<bf16x8*>(K + off) = rope8(kv, a, b);
}

// ---------------- windowed attention v4: pair-pipelined chunks (R8-exact) ----------
__global__ __launch_bounds__(256) void attn_kernel(const __bf16* __restrict__ Q,
                                                   const __bf16* __restrict__ K,
                                                   const __bf16* __restrict__ V,
                                                   __bf16* __restrict__ O) {
    __shared__ __align__(16) __bf16 Vt[64][328];     // V^T for the block's 320-key union
    __shared__ __align__(16) __bf16 Pl[4][16][80];   // per-wave P roundtrip, 2 slots

    int qt = blockIdx.x & 31;
    int bh = blockIdx.x >> 5;
    int q0 = qt * 64;
    int kbase0 = q0 - 128;
    const __bf16* Qbh = Q + (size_t)bh * SLEN * HDIM;
    const __bf16* Kbh = K + (size_t)bh * SLEN * HDIM;
    const __bf16* Vbh = V + (size_t)bh * SLEN * HDIM;

    int tid = threadIdx.x;
    int wave = tid >> 6, lane = tid & 63;
    int quad = lane >> 4, lrow = lane & 15;
    int wq0 = q0 + wave * 16;

    {
        int dchunk = wave * 16;
        #pragma unroll
        for (int k = 0; k < 5; k++) {
            int off = k * 64 + lane;                 // 0..319
            int krow = kbase0 + off;
            krow = min(max(krow, 0), SLEN - 1);      // clamp: masked later
            const __bf16* vp = Vbh + (size_t)krow * HDIM + dchunk;
            bf16x8 v0 = *reinterpret_cast<const bf16x8*>(vp);
            bf16x8 v1 = *reinterpret_cast<const bf16x8*>(vp + 8);
            #pragma unroll
            for (int i = 0; i < 8; i++) {
                Vt[dchunk + i][off] = v0[i];
                Vt[dchunk + 8 + i][off] = v1[i];
            }
        }
    }

    bf16x8 qb0 = *reinterpret_cast<const bf16x8*>(Qbh + (size_t)(wq0 + lrow) * HDIM + quad * 8);
    bf16x8 qb1 = *reinterpret_cast<const bf16x8*>(Qbh + (size_t)(wq0 + lrow) * HDIM + 32 + quad * 8);

    __syncthreads();   // Vt ready; no barriers after this point

    f32x4 zero = {0.f, 0.f, 0.f, 0.f};
    f32x4 acc[4], acc_l = zero;
    #pragma unroll
    for (int t = 0; t < 4; t++) acc[t] = zero;

    bf16x8 ones = { (__bf16)1.f, (__bf16)1.f, (__bf16)1.f, (__bf16)1.f,
                    (__bf16)1.f, (__bf16)1.f, (__bf16)1.f, (__bf16)1.f };

    int cbeg = wave >> 1;
    if (q0 < 128) { int e = (128 - q0) >> 5; if (e > cbeg) cbeg = e; }
    int cend = (16 * wave + 271) >> 5;
    { int e = (2175 - q0) >> 5; if (e < cend) cend = e; }

    auto loadK = [&](int c, bf16x8 (&kf)[2][2]) {
        int kb = kbase0 + c * 32;
        #pragma unroll
        for (int sub = 0; sub < 2; sub++) {
            int kr = kb + sub * 16 + lrow;
            int krc = min(max(kr, 0), SLEN - 1);     // clamp: safe past cend too
            const __bf16* kp = Kbh + (size_t)krc * HDIM;
            kf[sub][0] = *reinterpret_cast<const bf16x8*>(kp + quad * 8);
            kf[sub][1] = *reinterpret_cast<const bf16x8*>(kp + 32 + quad * 8);
        }
    };

    auto qkExp = [&](int c, bf16x8 (&kf)[2][2], int slot) {
        int kb = kbase0 + c * 32;
        int q = wq0 + lrow;
        #pragma unroll
        for (int sub = 0; sub < 2; sub++) {
            f32x4 st = __builtin_amdgcn_mfma_f32_16x16x32_bf16(kf[sub][0], qb0, zero, 0, 0, 0);
            st = __builtin_amdgcn_mfma_f32_16x16x32_bf16(kf[sub][1], qb1, st, 0, 0, 0);
            bf16x4 pk;
            #pragma unroll
            for (int r = 0; r < 4; r++) {
                int key = kb + sub * 16 + quad * 4 + r;
                int rel = key - q;
                bool valid = (rel >= -128) && (rel <= 128) && (key >= 0) && (key < SLEN);
                pk[r] = (__bf16)(valid ? __expf(st[r] * 0.125f) : 0.0f);
            }
            *reinterpret_cast<bf16x4*>(&Pl[wave][lrow][slot * 40 + sub * 16 + quad * 4]) = pk;
        }
    };

    auto pv = [&](int c, int slot) {
        int loc = c * 32;
        bf16x8 bp = *reinterpret_cast<const bf16x8*>(&Pl[wave][lrow][slot * 40 + quad * 8]);
        acc_l = __builtin_amdgcn_mfma_f32_16x16x32_bf16(ones, bp, acc_l, 0, 0, 0);
        #pragma unroll
        for (int t = 0; t < 4; t++) {
            bf16x8 va = *reinterpret_cast<const bf16x8*>(&Vt[t * 16 + lrow][loc + quad * 8]);
            acc[t] = __builtin_amdgcn_mfma_f32_16x16x32_bf16(va, bp, acc[t], 0, 0, 0);
        }
    };

    bf16x8 ka0[2][2], ka1[2][2];
    loadK(cbeg, ka0);
    loadK(cbeg + 1, ka1);    // clamped-safe even if cbeg+1 > cend
    int c = cbeg;
    while (c + 1 <= cend) {
        bf16x8 kn0[2][2], kn1[2][2];
        loadK(c + 2, kn0);
        loadK(c + 3, kn1);
        qkExp(c, ka0, 0);
        qkExp(c + 1, ka1, 1);
        asm volatile("s_waitcnt lgkmcnt(0)" ::: "memory");  // P writes visible (wave-local)
        pv(c, 0);
        pv(c + 1, 1);
        #pragma unroll
        for (int sub = 0; sub < 2; sub++) {
            ka0[sub][0] = kn0[sub][0]; ka0[sub][1] = kn0[sub][1];
            ka1[sub][0] = kn1[sub][0]; ka1[sub][1] = kn1[sub][1];
        }
        c += 2;
    }
    if (c <= cend) {         // odd-count tail
        qkExp(c, ka0, 0);
        asm volatile("s_waitcnt lgkmcnt(0)" ::: "memory");
        pv(c, 0);
    }

    float inv = 1.0f / acc_l[0];
    int b = bh >> 4, h = bh & 15;
    int q = wq0 + lrow;
    size_t base = ((size_t)b * SLEN + q) * 1024 + h * HDIM;
    #pragma unroll
    for (int t = 0; t < 4; t++) {
        bf16x4 o;
        #pragma unroll
        for (int r = 0; r < 4; r++) o[r] = (__bf16)(acc[t][r] * inv);
        *reinterpret_cast<bf16x4*>(&O[base + t * 16 + quad * 4]) = o;
    }
}

extern "C" void kernel_launch(void* const* d_in, const int* in_sizes, int n_in,
                              void* d_out, int out_size, void* d_ws, size_t ws_size,
                              hipStream_t stream) {
    const float* hidden = (const float*)d_in[0];   // [2,2048,1024]
    const float* Wqkv   = (const float*)d_in[1];   // [1024,3072]
    const float* bqkv   = (const float*)d_in[2];   // [3072]
    const float* Wo     = (const float*)d_in[3];   // [1024,1024]
    const float* bo     = (const float*)d_in[4];   // [1024]
    const float* rope   = (const float*)d_in[5];   // [256,32,2]
    float* out = (float*)d_out;                    // [2,2048,1024] fp32

    char* ws = (char*)d_ws;
    __bf16* A1  = (__bf16*)(ws);                   //  8 MiB: hidden bf16 [4096][1024]
    __bf16* Wt  = (__bf16*)(ws + 8388608);         //  6 MiB: Wqkv B-frag-linear
    __bf16* Wot = (__bf16*)(ws + 14680064);        //  2 MiB: Wo B-frag-linear
    __bf16* Qb  = (__bf16*)(ws + 16777216);        //  8 MiB: Q [B][H][S][64]
    __bf16* Kb  = (__bf16*)(ws + 25165824);        //  8 MiB: K
    __bf16* Vb  = (__bf16*)(ws + 33554432);        //  8 MiB: V
    __bf16* AO  = (__bf16*)(ws + 41943040);        //  8 MiB: attn out [4096][1024]

    // prep: cast hidden; weights -> B-frag-linear
    prep<<<8192, 256, 0, stream>>>(hidden, Wqkv, Wo, A1, Wt, Wot);

    // QKV projection: -> Q/K/V [B][H][S][64] (un-roped)
    gemm_bt<128><<<32 * 24, 256, 0, stream>>>(A1, Wt, bqkv, nullptr, Qb, Kb, Vb,
                                              4096, 3072, 1024, 1);
    // RoPE on Q,K in place (vectorized x8)
    rope_kernel<<<2048, 256, 0, stream>>>(Qb, Kb, rope);
    // windowed attention -> AO [4096][1024] bf16
    attn_kernel<<<1024, 256, 0, stream>>>(Qb, Kb, Vb, AO);
    // output projection: [4096,1024]@[1024,1024] + bias -> d_out fp32
    gemm_bt<64><<<32 * 16, 256, 0, stream>>>(AO, Wot, bo, out, nullptr, nullptr, nullptr,
                                             4096, 1024, 1024, 0);
}

// Round 12
// 177.884 us; speedup vs baseline: 1.0776x; 1.0080x over previous
//
#include <hip/hip_runtime.h>
#include <hip/hip_bf16.h>

typedef __bf16 bf16x8 __attribute__((ext_vector_type(8)));
typedef __bf16 bf16x4 __attribute__((ext_vector_type(4)));
typedef float f32x4 __attribute__((ext_vector_type(4)));

#define SLEN 2048
#define NHEADS 16
#define HDIM 64

// ---------------- prep (R8-exact) ----------------
// blocks 0..4095: cast hidden fp32->bf16; 4096..7167: Wqkv B-frag; 7168..8191: Wo B-frag
__global__ __launch_bounds__(256) void prep(const float* __restrict__ hidden,
                                            const float* __restrict__ Wqkv,
                                            const float* __restrict__ Wo,
                                            __bf16* __restrict__ A1,
                                            __bf16* __restrict__ Wt,
                                            __bf16* __restrict__ Wot) {
    int b = blockIdx.x;
    if (b < 4096) {
        int i = b * 256 + threadIdx.x;
        float4 v = reinterpret_cast<const float4*>(hidden)[i];
        bf16x4 o = { (__bf16)v.x, (__bf16)v.y, (__bf16)v.z, (__bf16)v.w };
        reinterpret_cast<bf16x4*>(A1)[i] = o;
        return;
    }
    __shared__ float tile[32][33];
    const float* W; __bf16* Dst; int N, n0, kc, bx, wn, j0, JNv;
    if (b < 7168) {
        int bb = b - 4096;                       // 96 n-tiles x 32 k-tiles
        int bx96 = bb % 96; kc = bb / 96;
        W = Wqkv; Dst = Wt; N = 3072;
        n0 = bx96 * 32;
        bx = bx96 >> 2; wn = (bx96 >> 1) & 1; j0 = (bx96 & 1) * 2; JNv = 4;
    } else {
        int bb = b - 7168;                       // 32 n-tiles x 32 k-tiles
        int bx32 = bb % 32; kc = bb / 32;
        W = Wo; Dst = Wot; N = 1024;
        n0 = bx32 * 32;
        bx = bx32 >> 1; wn = bx32 & 1; j0 = 0; JNv = 2;
    }
    int k0 = kc * 32;
    int tx = threadIdx.x & 31, ty = threadIdx.x >> 5;
    #pragma unroll
    for (int i = ty; i < 32; i += 8)
        tile[i][tx] = W[(size_t)(k0 + i) * N + n0 + tx];
    __syncthreads();
    if (threadIdx.x < 128) {
        int jh = threadIdx.x >> 6;
        int lane = threadIdx.x & 63;
        int lrow = lane & 15, quad = lane >> 4;
        bf16x8 val;
        #pragma unroll
        for (int i = 0; i < 8; i++)
            val[i] = (__bf16)tile[quad * 8 + i][jh * 16 + lrow];
        size_t idx = ((((size_t)(bx * 32 + kc) * 2 + wn) * JNv + (j0 + jh)) * 64 + lane);
        *reinterpret_cast<bf16x8*>(Dst + idx * 8) = val;
    }
}

// ---------------- GEMM: A in ping-pong LDS, B fragment-linear (R11-exact) -----------
// One barrier per K-iter; A+B for iter k+1 prefetched to regs before iter k's MFMAs.
// epi==0: fp32 out + bias; epi==1: split Q/K/V bf16 [B][H][S][D] + bias.
template <int TN>
__global__ __launch_bounds__(256) void gemm_bt(const __bf16* __restrict__ A,
                                               const __bf16* __restrict__ Bfrag,
                                               const float* __restrict__ bias,
                                               float* __restrict__ Cf,
                                               __bf16* __restrict__ Cq,
                                               __bf16* __restrict__ Ck,
                                               __bf16* __restrict__ Cv,
                                               int M, int N, int K, int epi) {
    constexpr int JN = TN / 32;   // n-frags per wave
    __shared__ __align__(16) __bf16 As[2][128 * 40];

    int nb = N / TN;
    int bx = blockIdx.x % nb;
    int by = blockIdx.x / nb;
    int row0 = by * 128, col0 = bx * TN;

    int tid = threadIdx.x;
    int wave = tid >> 6, lane = tid & 63;
    int quad = lane >> 4, lrow = lane & 15;
    int wm = wave >> 1, wn = wave & 1;

    int r1 = tid >> 2;
    int kk = (tid & 3) * 8;
    const __bf16* Aptr = A + (size_t)(row0 + r1) * K + kk;

    const __bf16* Bbase = Bfrag + ((size_t)(bx * 32) * 2 + wn) * JN * 512 + (size_t)lane * 8;

    f32x4 acc[4][JN];
    f32x4 zero = {0.f, 0.f, 0.f, 0.f};
    #pragma unroll
    for (int i = 0; i < 4; i++)
        #pragma unroll
        for (int j = 0; j < JN; j++) acc[i][j] = zero;

    int nkc = K >> 5;

    // prologue: stage kc=0 into buf 0; hold B frags for kc=0 in regs
    {
        bf16x8 a0 = *reinterpret_cast<const bf16x8*>(Aptr);
        bf16x8 a1 = *reinterpret_cast<const bf16x8*>(Aptr + (size_t)64 * K);
        *reinterpret_cast<bf16x8*>(&As[0][r1 * 40 + kk]) = a0;
        *reinterpret_cast<bf16x8*>(&As[0][(r1 + 64) * 40 + kk]) = a1;
    }
    bf16x8 bR[JN];
    #pragma unroll
    for (int j = 0; j < JN; j++)
        bR[j] = *reinterpret_cast<const bf16x8*>(Bbase + j * 512);
    __syncthreads();

    for (int kc = 0; kc < nkc; kc++) {
        int p = kc & 1;
        bool more = (kc + 1) < nkc;
        bf16x8 aN0, aN1, bN[JN];
        if (more) {
            int k0 = (kc + 1) * 32;
            aN0 = *reinterpret_cast<const bf16x8*>(Aptr + k0);
            aN1 = *reinterpret_cast<const bf16x8*>(Aptr + (size_t)64 * K + k0);
            #pragma unroll
            for (int j = 0; j < JN; j++)
                bN[j] = *reinterpret_cast<const bf16x8*>(Bbase + (size_t)(kc + 1) * JN * 1024 + j * 512);
        }

        bf16x8 af[4];
        #pragma unroll
        for (int i = 0; i < 4; i++)
            af[i] = *reinterpret_cast<const bf16x8*>(&As[p][(wm * 64 + i * 16 + lrow) * 40 + quad * 8]);
        #pragma unroll
        for (int i = 0; i < 4; i++)
            #pragma unroll
            for (int j = 0; j < JN; j++)
                acc[i][j] = __builtin_amdgcn_mfma_f32_16x16x32_bf16(af[i], bR[j], acc[i][j], 0, 0, 0);

        if (more) {
            *reinterpret_cast<bf16x8*>(&As[p ^ 1][r1 * 40 + kk]) = aN0;
            *reinterpret_cast<bf16x8*>(&As[p ^ 1][(r1 + 64) * 40 + kk]) = aN1;
            __syncthreads();
            #pragma unroll
            for (int j = 0; j < JN; j++) bR[j] = bN[j];
        }
    }

    int part = col0 >> 10;          // block-uniform
    #pragma unroll
    for (int i = 0; i < 4; i++) {
        int rowb = row0 + wm * 64 + i * 16 + quad * 4;
        #pragma unroll
        for (int j = 0; j < JN; j++) {
            int col = col0 + wn * (TN / 2) + j * 16 + lrow;
            float bsv = bias[col];
            #pragma unroll
            for (int r = 0; r < 4; r++) {
                int row = rowb + r;
                float v = acc[i][j][r] + bsv;
                if (epi == 0) {
                    Cf[(size_t)row * N + col] = v;
                } else {
                    int h = (col >> 6) & 15;
                    int d = col & 63;
                    int b = row >> 11;
                    int s = row & 2047;
                    __bf16* dst = (part == 0) ? Cq : ((part == 1) ? Ck : Cv);
                    dst[((size_t)(b * NHEADS + h) * SLEN + s) * HDIM + d] = (__bf16)v;
                }
            }
        }
    }
}

// ---- apply rope to an 8-elem group (4 complete pairs in-lane, no shuffles) ----
__device__ __forceinline__ bf16x8 rope8(bf16x8 v, f32x4 a, f32x4 b) {
    bf16x8 o;
    float e, od;
    e = (float)v[0]; od = (float)v[1];
    o[0] = (__bf16)(e * a[0] - od * a[1]); o[1] = (__bf16)(od * a[0] + e * a[1]);
    e = (float)v[2]; od = (float)v[3];
    o[2] = (__bf16)(e * a[2] - od * a[3]); o[3] = (__bf16)(od * a[2] + e * a[3]);
    e = (float)v[4]; od = (float)v[5];
    o[4] = (__bf16)(e * b[0] - od * b[1]); o[5] = (__bf16)(od * b[0] + e * b[1]);
    e = (float)v[6]; od = (float)v[7];
    o[6] = (__bf16)(e * b[2] - od * b[3]); o[7] = (__bf16)(od * b[2] + e * b[3]);
    return o;
}

// ---------------- RoPE in place on Q,K  [BH][S][64], vectorized x8 (R8-exact) ------
__global__ __launch_bounds__(256) void rope_kernel(__bf16* __restrict__ Q,
                                                   __bf16* __restrict__ K,
                                                   const float* __restrict__ rope) {
    int idx = blockIdx.x * 256 + threadIdx.x;        // [0, 32*2048*8)
    int chunk = idx & 7;
    int s = (idx >> 3) & 2047;
    int bh = idx >> 14;
    size_t off = ((size_t)bh * SLEN + s) * HDIM + chunk * 8;
    int pos = s & 255;
    const float* rp = rope + (size_t)pos * 64 + chunk * 8;
    f32x4 a = *reinterpret_cast<const f32x4*>(rp);
    f32x4 b = *reinterpret_cast<const f32x4*>(rp + 4);
    bf16x8 qv = *reinterpret_cast<bf16x8*>(Q + off);
    *reinterpret_cast<bf16x8*>(Q + off) = rope8(qv, a, b);
    bf16x8 kv = *reinterpret_cast<bf16x8*>(K + off);
    *reinterpret_cast<bf16x8*>(K + off) = rope8(kv, a, b);
}

// ---------------- windowed attention v4 + XCD-local block mapping ------------------
// bh = blk & 31, qt = blk >> 5: XCD x (= blk%8) serves heads {x,x+8,x+16,x+24} with
// qt sliding sequentially -> 4 heads' K+V (2 MB) resident in the 4 MiB per-XCD L2;
// chunk-loop K loads become L2 hits instead of cross-XCD HBM re-fetches.
__global__ __launch_bounds__(256) void attn_kernel(const __bf16* __restrict__ Q,
                                                   const __bf16* __restrict__ K,
                                                   const __bf16* __restrict__ V,
                                                   __bf16* __restrict__ O) {
    __shared__ __align__(16) __bf16 Vt[64][328];     // V^T for the block's 320-key union
    __shared__ __align__(16) __bf16 Pl[4][16][80];   // per-wave P roundtrip, 2 slots

    int bh = blockIdx.x & 31;                        // <- swapped (XCD locality)
    int qt = blockIdx.x >> 5;
    int q0 = qt * 64;
    int kbase0 = q0 - 128;
    const __bf16* Qbh = Q + (size_t)bh * SLEN * HDIM;
    const __bf16* Kbh = K + (size_t)bh * SLEN * HDIM;
    const __bf16* Vbh = V + (size_t)bh * SLEN * HDIM;

    int tid = threadIdx.x;
    int wave = tid >> 6, lane = tid & 63;
    int quad = lane >> 4, lrow = lane & 15;
    int wq0 = q0 + wave * 16;

    {
        int dchunk = wave * 16;
        #pragma unroll
        for (int k = 0; k < 5; k++) {
            int off = k * 64 + lane;                 // 0..319
            int krow = kbase0 + off;
            krow = min(max(krow, 0), SLEN - 1);      // clamp: masked later
            const __bf16* vp = Vbh + (size_t)krow * HDIM + dchunk;
            bf16x8 v0 = *reinterpret_cast<const bf16x8*>(vp);
            bf16x8 v1 = *reinterpret_cast<const bf16x8*>(vp + 8);
            #pragma unroll
            for (int i = 0; i < 8; i++) {
                Vt[dchunk + i][off] = v0[i];
                Vt[dchunk + 8 + i][off] = v1[i];
            }
        }
    }

    bf16x8 qb0 = *reinterpret_cast<const bf16x8*>(Qbh + (size_t)(wq0 + lrow) * HDIM + quad * 8);
    bf16x8 qb1 = *reinterpret_cast<const bf16x8*>(Qbh + (size_t)(wq0 + lrow) * HDIM + 32 + quad * 8);

    __syncthreads();   // Vt ready; no barriers after this point

    f32x4 zero = {0.f, 0.f, 0.f, 0.f};
    f32x4 acc[4], acc_l = zero;
    #pragma unroll
    for (int t = 0; t < 4; t++) acc[t] = zero;

    bf16x8 ones = { (__bf16)1.f, (__bf16)1.f, (__bf16)1.f, (__bf16)1.f,
                    (__bf16)1.f, (__bf16)1.f, (__bf16)1.f, (__bf16)1.f };

    int cbeg = wave >> 1;
    if (q0 < 128) { int e = (128 - q0) >> 5; if (e > cbeg) cbeg = e; }
    int cend = (16 * wave + 271) >> 5;
    { int e = (2175 - q0) >> 5; if (e < cend) cend = e; }

    auto loadK = [&](int c, bf16x8 (&kf)[2][2]) {
        int kb = kbase0 + c * 32;
        #pragma unroll
        for (int sub = 0; sub < 2; sub++) {
            int kr = kb + sub * 16 + lrow;
            int krc = min(max(kr, 0), SLEN - 1);     // clamp: safe past cend too
            const __bf16* kp = Kbh + (size_t)krc * HDIM;
            kf[sub][0] = *reinterpret_cast<const bf16x8*>(kp + quad * 8);
            kf[sub][1] = *reinterpret_cast<const bf16x8*>(kp + 32 + quad * 8);
        }
    };

    auto qkExp = [&](int c, bf16x8 (&kf)[2][2], int slot) {
        int kb = kbase0 + c * 32;
        int q = wq0 + lrow;
        #pragma unroll
        for (int sub = 0; sub < 2; sub++) {
            f32x4 st = __builtin_amdgcn_mfma_f32_16x16x32_bf16(kf[sub][0], qb0, zero, 0, 0, 0);
            st = __builtin_amdgcn_mfma_f32_16x16x32_bf16(kf[sub][1], qb1, st, 0, 0, 0);
            bf16x4 pk;
            #pragma unroll
            for (int r = 0; r < 4; r++) {
                int key = kb + sub * 16 + quad * 4 + r;
                int rel = key - q;
                bool valid = (rel >= -128) && (rel <= 128) && (key >= 0) && (key < SLEN);
                pk[r] = (__bf16)(valid ? __expf(st[r] * 0.125f) : 0.0f);
            }
            *reinterpret_cast<bf16x4*>(&Pl[wave][lrow][slot * 40 + sub * 16 + quad * 4]) = pk;
        }
    };

    auto pv = [&](int c, int slot) {
        int loc = c * 32;
        bf16x8 bp = *reinterpret_cast<const bf16x8*>(&Pl[wave][lrow][slot * 40 + quad * 8]);
        acc_l = __builtin_amdgcn_mfma_f32_16x16x32_bf16(ones, bp, acc_l, 0, 0, 0);
        #pragma unroll
        for (int t = 0; t < 4; t++) {
            bf16x8 va = *reinterpret_cast<const bf16x8*>(&Vt[t * 16 + lrow][loc + quad * 8]);
            acc[t] = __builtin_amdgcn_mfma_f32_16x16x32_bf16(va, bp, acc[t], 0, 0, 0);
        }
    };

    bf16x8 ka0[2][2], ka1[2][2];
    loadK(cbeg, ka0);
    loadK(cbeg + 1, ka1);    // clamped-safe even if cbeg+1 > cend
    int c = cbeg;
    while (c + 1 <= cend) {
        bf16x8 kn0[2][2], kn1[2][2];
        loadK(c + 2, kn0);
        loadK(c + 3, kn1);
        qkExp(c, ka0, 0);
        qkExp(c + 1, ka1, 1);
        asm volatile("s_waitcnt lgkmcnt(0)" ::: "memory");  // P writes visible (wave-local)
        pv(c, 0);
        pv(c + 1, 1);
        #pragma unroll
        for (int sub = 0; sub < 2; sub++) {
            ka0[sub][0] = kn0[sub][0]; ka0[sub][1] = kn0[sub][1];
            ka1[sub][0] = kn1[sub][0]; ka1[sub][1] = kn1[sub][1];
        }
        c += 2;
    }
    if (c <= cend) {         // odd-count tail
        qkExp(c, ka0, 0);
        asm volatile("s_waitcnt lgkmcnt(0)" ::: "memory");
        pv(c, 0);
    }

    float inv = 1.0f / acc_l[0];
    int b = bh >> 4, h = bh & 15;
    int q = wq0 + lrow;
    size_t base = ((size_t)b * SLEN + q) * 1024 + h * HDIM;
    #pragma unroll
    for (int t = 0; t < 4; t++) {
        bf16x4 o;
        #pragma unroll
        for (int r = 0; r < 4; r++) o[r] = (__bf16)(acc[t][r] * inv);
        *reinterpret_cast<bf16x4*>(&O[base + t * 16 + quad * 4]) = o;
    }
}

extern "C" void kernel_launch(void* const* d_in, const int* in_sizes, int n_in,
                              void* d_out, int out_size, void* d_ws, size_t ws_size,
                              hipStream_t stream) {
    const float* hidden = (const float*)d_in[0];   // [2,2048,1024]
    const float* Wqkv   = (const float*)d_in[1];   // [1024,3072]
    const float* bqkv   = (const float*)d_in[2];   // [3072]
    const float* Wo     = (const float*)d_in[3];   // [1024,1024]
    const float* bo     = (const float*)d_in[4];   // [1024]
    const float* rope   = (const float*)d_in[5];   // [256,32,2]
    float* out = (float*)d_out;                    // [2,2048,1024] fp32

    char* ws = (char*)d_ws;
    __bf16* A1  = (__bf16*)(ws);                   //  8 MiB: hidden bf16 [4096][1024]
    __bf16* Wt  = (__bf16*)(ws + 8388608);         //  6 MiB: Wqkv B-frag-linear
    __bf16* Wot = (__bf16*)(ws + 14680064);        //  2 MiB: Wo B-frag-linear
    __bf16* Qb  = (__bf16*)(ws + 16777216);        //  8 MiB: Q [B][H][S][64]
    __bf16* Kb  = (__bf16*)(ws + 25165824);        //  8 MiB: K
    __bf16* Vb  = (__bf16*)(ws + 33554432);        //  8 MiB: V
    __bf16* AO  = (__bf16*)(ws + 41943040);        //  8 MiB: attn out [4096][1024]

    // prep: cast hidden; weights -> B-frag-linear
    prep<<<8192, 256, 0, stream>>>(hidden, Wqkv, Wo, A1, Wt, Wot);

    // QKV projection: -> Q/K/V [B][H][S][64] (un-roped)
    gemm_bt<128><<<32 * 24, 256, 0, stream>>>(A1, Wt, bqkv, nullptr, Qb, Kb, Vb,
                                              4096, 3072, 1024, 1);
    // RoPE on Q,K in place (vectorized x8)
    rope_kernel<<<2048, 256, 0, stream>>>(Qb, Kb, rope);
    // windowed attention (XCD-local mapping) -> AO [4096][1024] bf16
    attn_kernel<<<1024, 256, 0, stream>>>(Qb, Kb, Vb, AO);
    // output projection: [4096,1024]@[1024,1024] + bias -> d_out fp32
    gemm_bt<64><<<32 * 16, 256, 0, stream>>>(AO, Wot, bo, out, nullptr, nullptr, nullptr,
                                             4096, 1024, 1024, 0);
}